// Round 4
// baseline (367.365 us; speedup 1.0000x reference)
//
#include <hip/hip_runtime.h>
#include <hip/hip_bf16.h>

// ---------------------------------------------------------------------------
// YOLOv3 post-processing pipeline (round 4):
//   K1 decode : plane-major mapping -> perfectly coalesced feature reads
//   K2 score  : u16 surrogate keys, 2 positions/thread, unroll-4 over classes
//   K3 topk   : 512 threads, packed u16 hist (20.5 KB LDS -> 32 waves/CU),
//               shuffle-based pivot scan (2 barriers vs 16)
//   K4 nms    : greedy NMS, one wave per row, shuffle broadcast
//   K5 final  : per-image top-100 of 8000
// ---------------------------------------------------------------------------

#define NTOT   22743      // 3*(19^2 + 38^2 + 76^2)
#define NCLS   80
#define TOPK   100
#define KPAD   22752      // row stride for keybuf (16B aligned, 8-div)
#define NVEC   2842       // 22736/8 full uint4 groups per row
#define SCORE_THR 0.2f
#define NMS_THR   0.3f

__device__ __forceinline__ float sig_exact(float x) {
    return 1.0f / (1.0f + expf(-x));          // precise OCML expf + IEEE div
}
__device__ __forceinline__ float sig_fast(float x) {
    // monotone surrogate, rel err ~1e-6 << 2^-7 bin margin
    return __builtin_amdgcn_rcpf(1.0f + __expf(-x));
}

// -------------------------- K1: decode (plane-major) ----------------------
__global__ __launch_bounds__(256) void k_decode(
    const float* __restrict__ f0, const float* __restrict__ f1,
    const float* __restrict__ f2, const float* __restrict__ anchors,
    const float* __restrict__ imshape, float4* __restrict__ boxes,
    float* __restrict__ conf_p, int total) {
    int gid = blockIdx.x * 256 + threadIdx.x;
    if (gid >= total) return;
    int b = gid / NTOT; int p = gid - b * NTOT;

    const float* f; int ghw, gw, l, off, a, s;
    if (p < 1083)      { f=f0; off=0;    ghw=361;  gw=19; l=0; int r=p;      a=r/361;  s=r-a*361;  }
    else if (p < 5415) { f=f1; off=1083; ghw=1444; gw=38; l=1; int r=p-1083; a=r/1444; s=r-a*1444; }
    else               { f=f2; off=5415; ghw=5776; gw=76; l=2; int r=p-5415; a=r/5776; s=r-a*5776; }
    int y = s / gw, x = s - y * gw;

    const float* q = f + ((size_t)(b * 255 + a * 85) * ghw + s);
    float tx = q[0], ty = q[ghw], tw = q[2*ghw], th = q[3*ghw], tc = q[4*ghw];

    int arow = (2 - l) * 3 + a;
    float aw = anchors[arow * 2], ah = anchors[arow * 2 + 1];
    float imh = imshape[0], imw = imshape[1];
    float gf = (float)gw;                       // gh == gw for all layers

    float bxx = (sig_exact(tx) + (float)x) / gf;
    float bxy = (sig_exact(ty) + (float)y) / gf;
    float bw  = expf(tw) * aw / 608.0f;
    float bh  = expf(th) * ah / 608.0f;

    float r  = fminf(608.0f / imh, 608.0f / imw);
    float nh = rintf(imh * r), nw = rintf(imw * r);
    float offy = (608.0f - nh) / 2.0f / 608.0f;
    float offx = (608.0f - nw) / 2.0f / 608.0f;
    float scy = 608.0f / nh, scx = 608.0f / nw;

    float cy = (bxy - offy) * scy;
    float cx = (bxx - offx) * scx;
    float hh = bh * scy, ww = bw * scx;

    int n = off + 3 * s + a;                    // anchor-major output index
    boxes[(size_t)b * NTOT + n] =
        make_float4((cy - hh / 2.0f) * imh, (cx - ww / 2.0f) * imw,
                    (cy + hh / 2.0f) * imh, (cx + ww / 2.0f) * imw);
    conf_p[(size_t)b * NTOT + p] = sig_exact(tc);
}

// -------------------------- K2: score (surrogate keys) --------------------
// grid = B * 48; chunk id -> (l, a, 512-wide s-chunk); 2 positions/thread.
__global__ __launch_bounds__(256) void k_score(
    const float* __restrict__ f0, const float* __restrict__ f1,
    const float* __restrict__ f2, const float* __restrict__ conf_p,
    unsigned short* __restrict__ keybuf) {
    const int cid = blockIdx.x % 48;
    const int b   = blockIdx.x / 48;
    int l, a, ch;
    if (cid < 3)       { l = 0; a = cid;               ch = 0;           }
    else if (cid < 12) { int t = cid - 3;  l = 1; a = t / 3;  ch = t - 3 * a;  }
    else               { int t = cid - 12; l = 2; a = t / 12; ch = t - 12 * a; }
    const int   ghw  = (l == 0) ? 361 : (l == 1) ? 1444 : 5776;
    const int   offs = (l == 0) ? 0   : (l == 1) ? 1083 : 5415;
    const float* f   = (l == 0) ? f0  : (l == 1) ? f1   : f2;

    const int s1 = ch * 512 + threadIdx.x;
    if (s1 >= ghw) return;
    const int s2 = s1 + 256;
    const bool a2 = (s2 < ghw);
    const int p1 = offs + a * ghw + s1;
    const float cf1 = conf_p[(size_t)b * NTOT + p1];
    const float cf2 = a2 ? conf_p[(size_t)b * NTOT + p1 + 256] : 0.0f;
    const float* cp = f + ((size_t)(b * 255 + a * 85 + 5) * ghw);
    unsigned short* kb = keybuf + (size_t)b * NCLS * KPAD + p1;

    #pragma unroll 4
    for (int c = 0; c < NCLS; ++c) {
        float t1 = cp[(size_t)c * ghw + s1];
        float k1 = cf1 * sig_fast(t1);
        kb[(size_t)c * KPAD] = (unsigned short)(__float_as_uint(k1) >> 16);
        if (a2) {
            float t2 = cp[(size_t)c * ghw + s2];
            float k2 = cf2 * sig_fast(t2);
            kb[(size_t)c * KPAD + 256] = (unsigned short)(__float_as_uint(k2) >> 16);
        }
    }
}

// ------------------ shared select helpers ---------------------------------
__device__ void find_pivot(unsigned* hist, int H, unsigned target,
                           unsigned* suf, unsigned* sh_p, unsigned* sh_above) {
    const int tid = threadIdx.x;
    const int per = H >> 8;
    if (tid < 256) {
        unsigned acc = 0;
        for (int u = 0; u < per; ++u) acc += hist[tid * per + u];
        suf[tid] = acc;
    }
    __syncthreads();
    for (int off = 1; off < 256; off <<= 1) {
        unsigned v = 0;
        if (tid < 256) v = (tid + off < 256) ? suf[tid + off] : 0u;
        __syncthreads();
        if (tid < 256) suf[tid] += v;
        __syncthreads();
    }
    if (tid < 256) {
        unsigned mysuf = suf[tid];
        unsigned nxt = (tid == 255) ? 0u : suf[tid + 1];
        if (mysuf >= target && nxt < target) {
            unsigned above = nxt;
            for (int h = tid * per + per - 1; h >= tid * per; --h) {
                unsigned c2 = above + hist[h];
                if (c2 >= target) { *sh_p = (unsigned)h; *sh_above = above; break; }
                above = c2;
            }
        }
    }
    __syncthreads();
}

template <int TPB>
__device__ void sortT512(unsigned long long* buf) {   // descending bitonic, 512
    const int tid = threadIdx.x;
    for (int k = 2; k <= 512; k <<= 1)
        for (int j = k >> 1; j > 0; j >>= 1) {
            __syncthreads();
            for (int i = tid; i < 512; i += TPB) {
                int ixj = i ^ j;
                if (ixj > i) {
                    unsigned long long a = buf[i], bb = buf[ixj];
                    bool desc = ((i & k) == 0);
                    if (desc ? (a < bb) : (a > bb)) { buf[i] = bb; buf[ixj] = a; }
                }
            }
        }
    __syncthreads();
}

// -------------------------- K3: per-class top-100 -------------------------
__device__ __forceinline__ void collect_cand(
    int b, int c, int p, const float* __restrict__ f0,
    const float* __restrict__ f1, const float* __restrict__ f2,
    const float* __restrict__ conf_p, unsigned long long* buf,
    unsigned* sh_cnt) {
    int a, s, offs, ghw;
    const float* f;
    if (p < 1083)      { offs = 0;    ghw = 361;  f = f0; int r = p;        a = r / 361;  s = r - a * 361;  }
    else if (p < 5415) { offs = 1083; ghw = 1444; f = f1; int r = p - 1083; a = r / 1444; s = r - a * 1444; }
    else               { offs = 5415; ghw = 5776; f = f2; int r = p - 5415; a = r / 5776; s = r - a * 5776; }
    float t  = f[((size_t)(b * 255 + a * 85 + 5 + c)) * ghw + s];
    float cf = conf_p[(size_t)b * NTOT + p];
    float sce = cf * sig_exact(t);
    int n = offs + 3 * s + a;
    unsigned slot = atomicAdd(sh_cnt, 1u);
    if (slot < 512)
        buf[slot] = (((unsigned long long)__float_as_uint(sce)) << 32)
                    | (unsigned)(~n);
}

__global__ __launch_bounds__(512, 8) void k_topk(
    const float* __restrict__ f0, const float* __restrict__ f1,
    const float* __restrict__ f2, const float* __restrict__ conf_p,
    const unsigned short* __restrict__ keybuf,
    const float4* __restrict__ boxes, float* __restrict__ top_s,
    float4* __restrict__ top_b) {
    __shared__ unsigned int histp[4096];           // packed u16x2: 8192 bins, 16 KB
    __shared__ unsigned long long buf[512];        // 4 KB
    __shared__ unsigned int wsum[4];
    __shared__ unsigned int sh_p, sh_above, sh_cnt;

    const int tid = threadIdx.x;
    const int row = blockIdx.x;
    const int b = row / NCLS, c = row - b * NCLS;
    const unsigned short* kr = keybuf + (size_t)row * KPAD;
    const uint4* kv = (const uint4*)kr;            // 8 keys per load

    for (int i = tid; i < 4096; i += 512) histp[i] = 0;
    if (tid == 0) sh_cnt = 0;
    __syncthreads();

    // pass 1: packed histogram of key>>1 (8192 bins)
    for (int g = tid; g < NVEC; g += 512) {
        uint4 v = kv[g];
        unsigned ks[8] = { v.x & 0xFFFFu, v.x >> 16, v.y & 0xFFFFu, v.y >> 16,
                           v.z & 0xFFFFu, v.z >> 16, v.w & 0xFFFFu, v.w >> 16 };
        #pragma unroll
        for (int j = 0; j < 8; ++j)
            atomicAdd(&histp[ks[j] >> 2], 1u << (((ks[j] >> 1) & 1u) * 16));
    }
    if (tid < NTOT - NVEC * 8) {                   // 7-key tail
        unsigned k = kr[NVEC * 8 + tid];
        atomicAdd(&histp[k >> 2], 1u << (((k >> 1) & 1u) * 16));
    }
    __syncthreads();

    // pivot: group t (tid<256) covers bins [t*32,t*32+32) = words [t*16,t*16+16)
    {
        const int lane = tid & 63;
        unsigned own = 0;
        if (tid < 256) {
            #pragma unroll
            for (int u = 0; u < 16; ++u) {
                unsigned w = histp[tid * 16 + u];
                own += (w & 0xFFFFu) + (w >> 16);
            }
        }
        unsigned acc = own;                        // wave-level suffix scan
        #pragma unroll
        for (int d = 1; d < 64; d <<= 1) {
            unsigned v = __shfl_down(acc, d, 64);
            if (lane + d < 64) acc += v;
        }
        if (tid < 256 && lane == 0) wsum[tid >> 6] = acc;
        __syncthreads();
        if (tid < 256) {
            unsigned tail = 0;
            for (int w2 = (tid >> 6) + 1; w2 < 4; ++w2) tail += wsum[w2];
            unsigned suft = acc + tail;            // suffix incl own group
            unsigned nxt  = suft - own;            // suffix of groups above
            if (suft >= TOPK && nxt < TOPK) {
                unsigned above = nxt;
                for (int bb = 31; bb >= 0; --bb) {
                    unsigned w = histp[tid * 16 + (bb >> 1)];
                    unsigned cnt = (bb & 1) ? (w >> 16) : (w & 0xFFFFu);
                    if (above + cnt >= TOPK) {
                        sh_p = (unsigned)(tid * 32 + bb); sh_above = above; break;
                    }
                    above += cnt;
                }
            }
        }
        __syncthreads();
    }
    const unsigned kthr = sh_p > 0 ? ((sh_p - 1) << 1) : 0u;  // one-bin margin

    // pass 2: collect candidates (keys L2-hot), exact rescore
    for (int g = tid; g < NVEC; g += 512) {
        uint4 v = kv[g];
        unsigned ks[8] = { v.x & 0xFFFFu, v.x >> 16, v.y & 0xFFFFu, v.y >> 16,
                           v.z & 0xFFFFu, v.z >> 16, v.w & 0xFFFFu, v.w >> 16 };
        #pragma unroll
        for (int j = 0; j < 8; ++j)
            if (ks[j] >= kthr)
                collect_cand(b, c, g * 8 + j, f0, f1, f2, conf_p, buf, &sh_cnt);
    }
    if (tid < NTOT - NVEC * 8) {
        int p = NVEC * 8 + tid;
        if ((unsigned)kr[p] >= kthr)
            collect_cand(b, c, p, f0, f1, f2, conf_p, buf, &sh_cnt);
    }
    __syncthreads();
    unsigned M = sh_cnt; if (M > 512) M = 512;
    for (int i = tid; i < 512; i += 512) if ((unsigned)i >= M) buf[i] = 0ull;
    __syncthreads();
    sortT512<512>(buf);

    if (tid < TOPK) {
        unsigned long long k = buf[tid];
        unsigned bits = (unsigned)(k >> 32);
        int n = (int)(~(unsigned)k);
        top_s[row * TOPK + tid] = __uint_as_float(bits);
        top_b[row * TOPK + tid] = boxes[(size_t)b * NTOT + n];
    }
}

// -------------------------- K4: greedy NMS (wave per row) -----------------
__global__ __launch_bounds__(256) void k_nms(
    const float* __restrict__ top_s, const float4* __restrict__ top_b,
    float* __restrict__ cand) {
    const int lane = threadIdx.x & 63;
    const int row  = blockIdx.x * 4 + (threadIdx.x >> 6);
    const float4* bb = top_b + (size_t)row * TOPK;
    const float*  ss = top_s + (size_t)row * TOPK;

    const int j0 = lane, j1 = lane + 64;
    const bool v1 = (j1 < TOPK);
    float4 B0 = bb[j0];
    float  s0 = ss[j0];
    float4 B1 = v1 ? bb[j1] : make_float4(0.f, 0.f, 0.f, 0.f);
    float  s1 = v1 ? ss[j1] : -1.0f;
    float ar0 = fmaxf(B0.z - B0.x, 0.f) * fmaxf(B0.w - B0.y, 0.f);
    float ar1 = fmaxf(B1.z - B1.x, 0.f) * fmaxf(B1.w - B1.y, 0.f);
    int sup0 = 0, sup1 = 0;

    for (int i = 0; i < TOPK; ++i) {
        const int src = i & 63;
        const bool hi = (i >= 64);
        float yi1 = __shfl(hi ? B1.x : B0.x, src, 64);
        float xi1 = __shfl(hi ? B1.y : B0.y, src, 64);
        float yi2 = __shfl(hi ? B1.z : B0.z, src, 64);
        float xi2 = __shfl(hi ? B1.w : B0.w, src, 64);
        float si  = __shfl(hi ? s1   : s0,   src, 64);
        int  supi = __shfl(hi ? sup1 : sup0, src, 64);
        bool keep_i = (si >= SCORE_THR) && (supi == 0);
        if (keep_i) {
            float ari = fmaxf(yi2 - yi1, 0.f) * fmaxf(xi2 - xi1, 0.f);
            if (j0 > i) {
                float ty1 = fmaxf(yi1, B0.x), tx1 = fmaxf(xi1, B0.y);
                float ty2 = fminf(yi2, B0.z), tx2 = fminf(xi2, B0.w);
                float inter = fmaxf(ty2 - ty1, 0.f) * fmaxf(tx2 - tx1, 0.f);
                float iou = inter / (ari + ar0 - inter + 1e-9f);
                if (iou > NMS_THR) sup0 = 1;
            }
            if (v1 && j1 > i) {
                float ty1 = fmaxf(yi1, B1.x), tx1 = fmaxf(xi1, B1.y);
                float ty2 = fminf(yi2, B1.z), tx2 = fminf(xi2, B1.w);
                float inter = fmaxf(ty2 - ty1, 0.f) * fmaxf(tx2 - tx1, 0.f);
                float iou = inter / (ari + ar1 - inter + 1e-9f);
                if (iou > NMS_THR) sup1 = 1;
            }
        }
    }
    cand[(size_t)row * TOPK + j0] = (s0 >= SCORE_THR && sup0 == 0) ? s0 : -1.0f;
    if (v1)
        cand[(size_t)row * TOPK + j1] = (s1 >= SCORE_THR && sup1 == 0) ? s1 : -1.0f;
}

// -------------------------- K5: per-image top-100 -------------------------
__global__ __launch_bounds__(256) void k_final(
    const float* __restrict__ cand, const float4* __restrict__ top_b,
    float* __restrict__ out) {
    __shared__ float cs[8000];                     // 32 KB
    __shared__ unsigned int hist[4096];            // 16 KB
    __shared__ unsigned long long buf[512];
    __shared__ unsigned int suf[256];
    __shared__ unsigned int sh_kp, sh_p1, sh_above1, sh_p2, sh_above2, sh_cnt;

    const int tid = threadIdx.x, b = blockIdx.x;
    if (tid == 0) { sh_kp = 0; sh_cnt = 0; }
    for (int i = tid; i < 4096; i += 256) hist[i] = 0;
    __syncthreads();

    unsigned lk = 0;
    for (int i = tid; i < 8000; i += 256) {
        float v = cand[b * 8000 + i];
        cs[i] = v;
        if (v > -0.5f) lk++;
    }
    atomicAdd(&sh_kp, lk);
    __syncthreads();
    unsigned Kp = sh_kp;

    if (Kp >= TOPK) {
        for (int i = tid; i < 8000; i += 256)
            if (cs[i] > -0.5f) atomicAdd(&hist[__float_as_uint(cs[i]) >> 19], 1u);
        __syncthreads();
        find_pivot(hist, 2048, TOPK, suf, &sh_p1, &sh_above1);
        unsigned p1 = sh_p1, above1 = sh_above1;
        for (int i = tid; i < 4096; i += 256) hist[i] = 0;
        __syncthreads();
        for (int i = tid; i < 8000; i += 256) {
            float v = cs[i];
            if (v > -0.5f) {
                unsigned bits = __float_as_uint(v);
                if ((bits >> 19) == p1) atomicAdd(&hist[(bits >> 7) & 0xFFFu], 1u);
            }
        }
        __syncthreads();
        find_pivot(hist, 4096, TOPK - above1, suf, &sh_p2, &sh_above2);
        unsigned p2 = sh_p2;
        for (int i = tid; i < 8000; i += 256) {
            float v = cs[i];
            if (v > -0.5f) {
                unsigned bits = __float_as_uint(v);
                unsigned b1 = bits >> 19;
                if (b1 > p1 || (b1 == p1 && ((bits >> 7) & 0xFFFu) >= p2)) {
                    unsigned slot = atomicAdd(&sh_cnt, 1u);
                    if (slot < 512)
                        buf[slot] = (((unsigned long long)bits) << 32) | (unsigned)(~i);
                }
            }
        }
        __syncthreads();
        unsigned M = sh_cnt; if (M > 512) M = 512;
        for (int i = tid; i < 512; i += 256) if ((unsigned)i >= M) buf[i] = 0ull;
    } else {
        for (int i = tid; i < 512; i += 256) buf[i] = 0ull;
        __syncthreads();
        for (int i = tid; i < 8000; i += 256) {
            float v = cs[i];
            if (v > -0.5f) {
                unsigned slot = atomicAdd(&sh_cnt, 1u);
                buf[slot] = (((unsigned long long)__float_as_uint(v)) << 32) | (unsigned)(~i);
            }
        }
        __syncthreads();
        if (tid == 0) {
            unsigned need = TOPK - Kp, got = 0;
            for (int i = 0; i < 8000 && got < need; ++i)
                if (cs[i] <= -0.5f) { buf[Kp + got] = (unsigned)(~i); got++; }
        }
    }
    __syncthreads();
    sortT512<256>(buf);

    if (tid < TOPK) {
        unsigned long long k = buf[tid];
        int i = (int)(~(unsigned)k);
        int c = i / TOPK; int kk = i - c * TOPK;
        float4 bb = top_b[((size_t)b * NCLS + c) * TOPK + kk];
        int base = (b * TOPK + tid) * 6;
        out[base + 0] = bb.x; out[base + 1] = bb.y;
        out[base + 2] = bb.z; out[base + 3] = bb.w;
        out[base + 4] = cs[i]; out[base + 5] = (float)c;
    }
}

// ---------------------------------------------------------------------------
extern "C" void kernel_launch(void* const* d_in, const int* in_sizes, int n_in,
                              void* d_out, int out_size, void* d_ws, size_t ws_size,
                              hipStream_t stream) {
    (void)n_in; (void)out_size; (void)ws_size;
    const float* f0      = (const float*)d_in[0];
    const float* f1      = (const float*)d_in[1];
    const float* f2      = (const float*)d_in[2];
    const float* anchors = (const float*)d_in[3];
    const float* imshape = (const float*)d_in[4];
    const int B = in_sizes[0] / (255 * 19 * 19);

    char* ws = (char*)d_ws;
    size_t o = 0;
    unsigned short* keybuf = (unsigned short*)(ws + o);
    o += (size_t)B * NCLS * KPAD * sizeof(unsigned short);   // 58.2 MB
    float4* boxes  = (float4*)(ws + o); o += (size_t)B * NTOT * sizeof(float4);
    float*  conf_p = (float*)(ws + o);  o += (size_t)B * NTOT * sizeof(float);
    float*  top_s  = (float*)(ws + o);  o += (size_t)B * NCLS * TOPK * sizeof(float);
    float4* top_b  = (float4*)(ws + o); o += (size_t)B * NCLS * TOPK * sizeof(float4);
    float*  cand   = (float*)(ws + o);  o += (size_t)B * NCLS * TOPK * sizeof(float);
    float*  out    = (float*)d_out;

    const int total = B * NTOT;
    k_decode<<<(total + 255) / 256, 256, 0, stream>>>(f0, f1, f2, anchors, imshape,
                                                      boxes, conf_p, total);
    k_score<<<B * 48, 256, 0, stream>>>(f0, f1, f2, conf_p, keybuf);
    k_topk<<<B * NCLS, 512, 0, stream>>>(f0, f1, f2, conf_p, keybuf, boxes,
                                         top_s, top_b);
    k_nms<<<(B * NCLS) / 4, 256, 0, stream>>>(top_s, top_b, cand);
    k_final<<<B, 256, 0, stream>>>(cand, top_b, out);
}

// Round 5
// 296.485 us; speedup vs baseline: 1.2391x; 1.2391x over previous
//
#include <hip/hip_runtime.h>
#include <hip/hip_bf16.h>

// ---------------------------------------------------------------------------
// YOLOv3 post-processing pipeline (round 5):
//   K1 decode : plane-major coalesced feature reads; conf written in q-order
//   K2 score  : STREAMING — 1 thread = 4 keys, float4 logit + float4 conf
//               loads, ushort4 store; 32k blocks; layer2-first q layout so
//               every vector access is aligned (layer0 scalar, 4% of work)
//   K3 topk   : 512 thr, packed u16 hist (20.5 KB LDS), shuffle pivot scan,
//               collect+exact-rescore, bitonic sort
//   K4 nms    : greedy NMS, one wave per row, shuffle broadcast
//   K5 final  : per-image top-100 of 8000
// ---------------------------------------------------------------------------

#define NTOT   22743      // 3*(19^2 + 38^2 + 76^2)
#define NCLS   80
#define TOPK   100
#define KPAD   22752      // row stride for keybuf/conf (16B aligned, 8-div)
#define NVEC   2842       // full uint4 groups per key row (22736 keys)
// q-layout region starts (layer2 first; all l1/l2 starts % 4 == 0):
//   l2: a*5776            (0, 5776, 11552)
//   l1: 17328 + a*1444    (17328, 18772, 20216)
//   l0: 21660 + a*361
#define Q_L1   17328
#define Q_L0   21660
#define SCORE_THR 0.2f
#define NMS_THR   0.3f

__device__ __forceinline__ float sig_exact(float x) {
    return 1.0f / (1.0f + expf(-x));          // precise OCML expf + IEEE div
}
__device__ __forceinline__ float sig_fast(float x) {
    // monotone surrogate, rel err ~1e-6 << 2^-7 bin margin
    return __builtin_amdgcn_rcpf(1.0f + __expf(-x));
}

// -------------------------- K1: decode (plane-major) ----------------------
__global__ __launch_bounds__(256) void k_decode(
    const float* __restrict__ f0, const float* __restrict__ f1,
    const float* __restrict__ f2, const float* __restrict__ anchors,
    const float* __restrict__ imshape, float4* __restrict__ boxes,
    float* __restrict__ conf_q, int total) {
    int gid = blockIdx.x * 256 + threadIdx.x;
    if (gid >= total) return;
    int b = gid / NTOT; int p = gid - b * NTOT;

    const float* f; int ghw, gw, l, off, a, s;
    if (p < 1083)      { f=f0; off=0;    ghw=361;  gw=19; l=0; int r=p;      a=r/361;  s=r-a*361;  }
    else if (p < 5415) { f=f1; off=1083; ghw=1444; gw=38; l=1; int r=p-1083; a=r/1444; s=r-a*1444; }
    else               { f=f2; off=5415; ghw=5776; gw=76; l=2; int r=p-5415; a=r/5776; s=r-a*5776; }
    int y = s / gw, x = s - y * gw;

    const float* q = f + ((size_t)(b * 255 + a * 85) * ghw + s);
    float tx = q[0], ty = q[ghw], tw = q[2*ghw], th = q[3*ghw], tc = q[4*ghw];

    int arow = (2 - l) * 3 + a;
    float aw = anchors[arow * 2], ah = anchors[arow * 2 + 1];
    float imh = imshape[0], imw = imshape[1];
    float gf = (float)gw;                       // gh == gw for all layers

    float bxx = (sig_exact(tx) + (float)x) / gf;
    float bxy = (sig_exact(ty) + (float)y) / gf;
    float bw  = expf(tw) * aw / 608.0f;
    float bh  = expf(th) * ah / 608.0f;

    float r  = fminf(608.0f / imh, 608.0f / imw);
    float nh = rintf(imh * r), nw = rintf(imw * r);
    float offy = (608.0f - nh) / 2.0f / 608.0f;
    float offx = (608.0f - nw) / 2.0f / 608.0f;
    float scy = 608.0f / nh, scx = 608.0f / nw;

    float cy = (bxy - offy) * scy;
    float cx = (bxx - offx) * scx;
    float hh = bh * scy, ww = bw * scx;

    int n = off + 3 * s + a;                    // anchor-major output index
    boxes[(size_t)b * NTOT + n] =
        make_float4((cy - hh / 2.0f) * imh, (cx - ww / 2.0f) * imw,
                    (cy + hh / 2.0f) * imh, (cx + ww / 2.0f) * imw);
    int qi = (l == 2) ? (a * 5776 + s)
           : (l == 1) ? (Q_L1 + a * 1444 + s)
                      : (Q_L0 + a * 361 + s);
    conf_q[(size_t)b * KPAD + qi] = sig_exact(tc);
}

// -------------------------- K2: score (streaming) -------------------------
// 1 thread = 4 keys (layers 1/2) or 1 key (layer 0). Flat gid decode:
//   per-b work: segA (l2 vec4) 346560, segB (l1 vec4) 86640, segC (l0) 86640
#define SEG_A  346560
#define SEG_AB 433200
#define SEG_T  519840
__global__ __launch_bounds__(256) void k_score(
    const float* __restrict__ f0, const float* __restrict__ f1,
    const float* __restrict__ f2, const float* __restrict__ conf_q,
    unsigned short* __restrict__ keybuf, int total) {
    int gid = blockIdx.x * 256 + threadIdx.x;
    if (gid >= total) return;
    const int b = gid / SEG_T;
    const int w = gid - b * SEG_T;

    if (w < SEG_AB) {                       // vectorized: layer 2 or layer 1
        const float* f; int a, c, s, qbase, ghw;
        if (w < SEG_A) {                    // layer 2: 80*1444 float4 per a
            a = w / 115520; int r = w - a * 115520;
            c = r / 1444;   s = (r - c * 1444) * 4;
            f = f2; ghw = 5776; qbase = a * 5776;
        } else {                            // layer 1: 80*361 float4 per a
            int t = w - SEG_A;
            a = t / 28880;  int r = t - a * 28880;
            c = r / 361;    s = (r - c * 361) * 4;
            f = f1; ghw = 1444; qbase = Q_L1 + a * 1444;
        }
        const float4 lg = *(const float4*)(f + ((size_t)(b * 255 + a * 85 + 5 + c) * ghw + s));
        const float4 cf = *(const float4*)(conf_q + (size_t)b * KPAD + qbase + s);
        ushort4 k;
        k.x = (unsigned short)(__float_as_uint(cf.x * sig_fast(lg.x)) >> 16);
        k.y = (unsigned short)(__float_as_uint(cf.y * sig_fast(lg.y)) >> 16);
        k.z = (unsigned short)(__float_as_uint(cf.z * sig_fast(lg.z)) >> 16);
        k.w = (unsigned short)(__float_as_uint(cf.w * sig_fast(lg.w)) >> 16);
        *(ushort4*)(keybuf + ((size_t)(b * NCLS + c)) * KPAD + qbase + s) = k;
    } else {                                // layer 0: scalar
        int t = w - SEG_AB;
        int a = t / 28880;  int r = t - a * 28880;
        int c = r / 361;    int s = r - c * 361;
        int qi = Q_L0 + a * 361 + s;
        float lg = f0[((size_t)(b * 255 + a * 85 + 5 + c) * 361 + s)];
        float cf = conf_q[(size_t)b * KPAD + qi];
        keybuf[((size_t)(b * NCLS + c)) * KPAD + qi] =
            (unsigned short)(__float_as_uint(cf * sig_fast(lg)) >> 16);
    }
}

// ------------------ shared select helpers ---------------------------------
__device__ void find_pivot(unsigned* hist, int H, unsigned target,
                           unsigned* suf, unsigned* sh_p, unsigned* sh_above) {
    const int tid = threadIdx.x;
    const int per = H >> 8;
    if (tid < 256) {
        unsigned acc = 0;
        for (int u = 0; u < per; ++u) acc += hist[tid * per + u];
        suf[tid] = acc;
    }
    __syncthreads();
    for (int off = 1; off < 256; off <<= 1) {
        unsigned v = 0;
        if (tid < 256) v = (tid + off < 256) ? suf[tid + off] : 0u;
        __syncthreads();
        if (tid < 256) suf[tid] += v;
        __syncthreads();
    }
    if (tid < 256) {
        unsigned mysuf = suf[tid];
        unsigned nxt = (tid == 255) ? 0u : suf[tid + 1];
        if (mysuf >= target && nxt < target) {
            unsigned above = nxt;
            for (int h = tid * per + per - 1; h >= tid * per; --h) {
                unsigned c2 = above + hist[h];
                if (c2 >= target) { *sh_p = (unsigned)h; *sh_above = above; break; }
                above = c2;
            }
        }
    }
    __syncthreads();
}

template <int TPB>
__device__ void sortT512(unsigned long long* buf) {   // descending bitonic, 512
    const int tid = threadIdx.x;
    for (int k = 2; k <= 512; k <<= 1)
        for (int j = k >> 1; j > 0; j >>= 1) {
            __syncthreads();
            for (int i = tid; i < 512; i += TPB) {
                int ixj = i ^ j;
                if (ixj > i) {
                    unsigned long long a = buf[i], bb = buf[ixj];
                    bool desc = ((i & k) == 0);
                    if (desc ? (a < bb) : (a > bb)) { buf[i] = bb; buf[ixj] = a; }
                }
            }
        }
    __syncthreads();
}

// -------------------------- K3: per-class top-100 -------------------------
// q (layer2-first layout) -> exact rescore + anchor-major n
__device__ __forceinline__ void collect_cand(
    int b, int c, int q, const float* __restrict__ f0,
    const float* __restrict__ f1, const float* __restrict__ f2,
    const float* __restrict__ conf_q, unsigned long long* buf,
    unsigned* sh_cnt) {
    int a, s, nbase, ghw;
    const float* f;
    if (q < Q_L1)      { a = q / 5776;  s = q - a * 5776;  f = f2; ghw = 5776; nbase = 5415; }
    else if (q < Q_L0) { int r = q - Q_L1; a = r / 1444; s = r - a * 1444; f = f1; ghw = 1444; nbase = 1083; }
    else               { int r = q - Q_L0; a = r / 361;  s = r - a * 361;  f = f0; ghw = 361;  nbase = 0;    }
    float t  = f[((size_t)(b * 255 + a * 85 + 5 + c)) * ghw + s];
    float cf = conf_q[(size_t)b * KPAD + q];
    float sce = cf * sig_exact(t);
    int n = nbase + 3 * s + a;
    unsigned slot = atomicAdd(sh_cnt, 1u);
    if (slot < 512)
        buf[slot] = (((unsigned long long)__float_as_uint(sce)) << 32)
                    | (unsigned)(~n);
}

__global__ __launch_bounds__(512, 8) void k_topk(
    const float* __restrict__ f0, const float* __restrict__ f1,
    const float* __restrict__ f2, const float* __restrict__ conf_q,
    const unsigned short* __restrict__ keybuf,
    const float4* __restrict__ boxes, float* __restrict__ top_s,
    float4* __restrict__ top_b) {
    __shared__ unsigned int histp[4096];           // packed u16x2: 8192 bins, 16 KB
    __shared__ unsigned long long buf[512];        // 4 KB
    __shared__ unsigned int wsum[4];
    __shared__ unsigned int sh_p, sh_above, sh_cnt;

    const int tid = threadIdx.x;
    const int row = blockIdx.x;
    const int b = row / NCLS, c = row - b * NCLS;
    const unsigned short* kr = keybuf + (size_t)row * KPAD;
    const uint4* kv = (const uint4*)kr;            // 8 keys per load

    for (int i = tid; i < 4096; i += 512) histp[i] = 0;
    if (tid == 0) sh_cnt = 0;
    __syncthreads();

    // pass 1: packed histogram of key>>1 (8192 bins)
    for (int g = tid; g < NVEC; g += 512) {
        uint4 v = kv[g];
        unsigned ks[8] = { v.x & 0xFFFFu, v.x >> 16, v.y & 0xFFFFu, v.y >> 16,
                           v.z & 0xFFFFu, v.z >> 16, v.w & 0xFFFFu, v.w >> 16 };
        #pragma unroll
        for (int j = 0; j < 8; ++j)
            atomicAdd(&histp[ks[j] >> 2], 1u << (((ks[j] >> 1) & 1u) * 16));
    }
    if (tid < NTOT - NVEC * 8) {                   // 7-key tail
        unsigned k = kr[NVEC * 8 + tid];
        atomicAdd(&histp[k >> 2], 1u << (((k >> 1) & 1u) * 16));
    }
    __syncthreads();

    // pivot: group t (tid<256) covers bins [t*32,t*32+32) = words [t*16,t*16+16)
    {
        const int lane = tid & 63;
        unsigned own = 0;
        if (tid < 256) {
            #pragma unroll
            for (int u = 0; u < 16; ++u) {
                unsigned w = histp[tid * 16 + u];
                own += (w & 0xFFFFu) + (w >> 16);
            }
        }
        unsigned acc = own;                        // wave-level suffix scan
        #pragma unroll
        for (int d = 1; d < 64; d <<= 1) {
            unsigned v = __shfl_down(acc, d, 64);
            if (lane + d < 64) acc += v;
        }
        if (tid < 256 && lane == 0) wsum[tid >> 6] = acc;
        __syncthreads();
        if (tid < 256) {
            unsigned tail = 0;
            for (int w2 = (tid >> 6) + 1; w2 < 4; ++w2) tail += wsum[w2];
            unsigned suft = acc + tail;            // suffix incl own group
            unsigned nxt  = suft - own;            // suffix of groups above
            if (suft >= TOPK && nxt < TOPK) {
                unsigned above = nxt;
                for (int bb = 31; bb >= 0; --bb) {
                    unsigned w = histp[tid * 16 + (bb >> 1)];
                    unsigned cnt = (bb & 1) ? (w >> 16) : (w & 0xFFFFu);
                    if (above + cnt >= TOPK) {
                        sh_p = (unsigned)(tid * 32 + bb); sh_above = above; break;
                    }
                    above += cnt;
                }
            }
        }
        __syncthreads();
    }
    const unsigned kthr = sh_p > 0 ? ((sh_p - 1) << 1) : 0u;  // one-bin margin

    // pass 2: collect candidates (keys L2-hot), exact rescore
    for (int g = tid; g < NVEC; g += 512) {
        uint4 v = kv[g];
        unsigned ks[8] = { v.x & 0xFFFFu, v.x >> 16, v.y & 0xFFFFu, v.y >> 16,
                           v.z & 0xFFFFu, v.z >> 16, v.w & 0xFFFFu, v.w >> 16 };
        #pragma unroll
        for (int j = 0; j < 8; ++j)
            if (ks[j] >= kthr)
                collect_cand(b, c, g * 8 + j, f0, f1, f2, conf_q, buf, &sh_cnt);
    }
    if (tid < NTOT - NVEC * 8) {
        int q = NVEC * 8 + tid;
        if ((unsigned)kr[q] >= kthr)
            collect_cand(b, c, q, f0, f1, f2, conf_q, buf, &sh_cnt);
    }
    __syncthreads();
    unsigned M = sh_cnt; if (M > 512) M = 512;
    for (int i = tid; i < 512; i += 512) if ((unsigned)i >= M) buf[i] = 0ull;
    __syncthreads();
    sortT512<512>(buf);

    if (tid < TOPK) {
        unsigned long long k = buf[tid];
        unsigned bits = (unsigned)(k >> 32);
        int n = (int)(~(unsigned)k);
        top_s[row * TOPK + tid] = __uint_as_float(bits);
        top_b[row * TOPK + tid] = boxes[(size_t)b * NTOT + n];
    }
}

// -------------------------- K4: greedy NMS (wave per row) -----------------
__global__ __launch_bounds__(256) void k_nms(
    const float* __restrict__ top_s, const float4* __restrict__ top_b,
    float* __restrict__ cand) {
    const int lane = threadIdx.x & 63;
    const int row  = blockIdx.x * 4 + (threadIdx.x >> 6);
    const float4* bb = top_b + (size_t)row * TOPK;
    const float*  ss = top_s + (size_t)row * TOPK;

    const int j0 = lane, j1 = lane + 64;
    const bool v1 = (j1 < TOPK);
    float4 B0 = bb[j0];
    float  s0 = ss[j0];
    float4 B1 = v1 ? bb[j1] : make_float4(0.f, 0.f, 0.f, 0.f);
    float  s1 = v1 ? ss[j1] : -1.0f;
    float ar0 = fmaxf(B0.z - B0.x, 0.f) * fmaxf(B0.w - B0.y, 0.f);
    float ar1 = fmaxf(B1.z - B1.x, 0.f) * fmaxf(B1.w - B1.y, 0.f);
    int sup0 = 0, sup1 = 0;

    for (int i = 0; i < TOPK; ++i) {
        const int src = i & 63;
        const bool hi = (i >= 64);
        float yi1 = __shfl(hi ? B1.x : B0.x, src, 64);
        float xi1 = __shfl(hi ? B1.y : B0.y, src, 64);
        float yi2 = __shfl(hi ? B1.z : B0.z, src, 64);
        float xi2 = __shfl(hi ? B1.w : B0.w, src, 64);
        float si  = __shfl(hi ? s1   : s0,   src, 64);
        int  supi = __shfl(hi ? sup1 : sup0, src, 64);
        bool keep_i = (si >= SCORE_THR) && (supi == 0);
        if (keep_i) {
            float ari = fmaxf(yi2 - yi1, 0.f) * fmaxf(xi2 - xi1, 0.f);
            if (j0 > i) {
                float ty1 = fmaxf(yi1, B0.x), tx1 = fmaxf(xi1, B0.y);
                float ty2 = fminf(yi2, B0.z), tx2 = fminf(xi2, B0.w);
                float inter = fmaxf(ty2 - ty1, 0.f) * fmaxf(tx2 - tx1, 0.f);
                float iou = inter / (ari + ar0 - inter + 1e-9f);
                if (iou > NMS_THR) sup0 = 1;
            }
            if (v1 && j1 > i) {
                float ty1 = fmaxf(yi1, B1.x), tx1 = fmaxf(xi1, B1.y);
                float ty2 = fminf(yi2, B1.z), tx2 = fminf(xi2, B1.w);
                float inter = fmaxf(ty2 - ty1, 0.f) * fmaxf(tx2 - tx1, 0.f);
                float iou = inter / (ari + ar1 - inter + 1e-9f);
                if (iou > NMS_THR) sup1 = 1;
            }
        }
    }
    cand[(size_t)row * TOPK + j0] = (s0 >= SCORE_THR && sup0 == 0) ? s0 : -1.0f;
    if (v1)
        cand[(size_t)row * TOPK + j1] = (s1 >= SCORE_THR && sup1 == 0) ? s1 : -1.0f;
}

// -------------------------- K5: per-image top-100 -------------------------
__global__ __launch_bounds__(256) void k_final(
    const float* __restrict__ cand, const float4* __restrict__ top_b,
    float* __restrict__ out) {
    __shared__ float cs[8000];                     // 32 KB
    __shared__ unsigned int hist[4096];            // 16 KB
    __shared__ unsigned long long buf[512];
    __shared__ unsigned int suf[256];
    __shared__ unsigned int sh_kp, sh_p1, sh_above1, sh_p2, sh_above2, sh_cnt;

    const int tid = threadIdx.x, b = blockIdx.x;
    if (tid == 0) { sh_kp = 0; sh_cnt = 0; }
    for (int i = tid; i < 4096; i += 256) hist[i] = 0;
    __syncthreads();

    unsigned lk = 0;
    for (int i = tid; i < 8000; i += 256) {
        float v = cand[b * 8000 + i];
        cs[i] = v;
        if (v > -0.5f) lk++;
    }
    atomicAdd(&sh_kp, lk);
    __syncthreads();
    unsigned Kp = sh_kp;

    if (Kp >= TOPK) {
        for (int i = tid; i < 8000; i += 256)
            if (cs[i] > -0.5f) atomicAdd(&hist[__float_as_uint(cs[i]) >> 19], 1u);
        __syncthreads();
        find_pivot(hist, 2048, TOPK, suf, &sh_p1, &sh_above1);
        unsigned p1 = sh_p1, above1 = sh_above1;
        for (int i = tid; i < 4096; i += 256) hist[i] = 0;
        __syncthreads();
        for (int i = tid; i < 8000; i += 256) {
            float v = cs[i];
            if (v > -0.5f) {
                unsigned bits = __float_as_uint(v);
                if ((bits >> 19) == p1) atomicAdd(&hist[(bits >> 7) & 0xFFFu], 1u);
            }
        }
        __syncthreads();
        find_pivot(hist, 4096, TOPK - above1, suf, &sh_p2, &sh_above2);
        unsigned p2 = sh_p2;
        for (int i = tid; i < 8000; i += 256) {
            float v = cs[i];
            if (v > -0.5f) {
                unsigned bits = __float_as_uint(v);
                unsigned b1 = bits >> 19;
                if (b1 > p1 || (b1 == p1 && ((bits >> 7) & 0xFFFu) >= p2)) {
                    unsigned slot = atomicAdd(&sh_cnt, 1u);
                    if (slot < 512)
                        buf[slot] = (((unsigned long long)bits) << 32) | (unsigned)(~i);
                }
            }
        }
        __syncthreads();
        unsigned M = sh_cnt; if (M > 512) M = 512;
        for (int i = tid; i < 512; i += 256) if ((unsigned)i >= M) buf[i] = 0ull;
    } else {
        for (int i = tid; i < 512; i += 256) buf[i] = 0ull;
        __syncthreads();
        for (int i = tid; i < 8000; i += 256) {
            float v = cs[i];
            if (v > -0.5f) {
                unsigned slot = atomicAdd(&sh_cnt, 1u);
                buf[slot] = (((unsigned long long)__float_as_uint(v)) << 32) | (unsigned)(~i);
            }
        }
        __syncthreads();
        if (tid == 0) {
            unsigned need = TOPK - Kp, got = 0;
            for (int i = 0; i < 8000 && got < need; ++i)
                if (cs[i] <= -0.5f) { buf[Kp + got] = (unsigned)(~i); got++; }
        }
    }
    __syncthreads();
    sortT512<256>(buf);

    if (tid < TOPK) {
        unsigned long long k = buf[tid];
        int i = (int)(~(unsigned)k);
        int c = i / TOPK; int kk = i - c * TOPK;
        float4 bb = top_b[((size_t)b * NCLS + c) * TOPK + kk];
        int base = (b * TOPK + tid) * 6;
        out[base + 0] = bb.x; out[base + 1] = bb.y;
        out[base + 2] = bb.z; out[base + 3] = bb.w;
        out[base + 4] = cs[i]; out[base + 5] = (float)c;
    }
}

// ---------------------------------------------------------------------------
extern "C" void kernel_launch(void* const* d_in, const int* in_sizes, int n_in,
                              void* d_out, int out_size, void* d_ws, size_t ws_size,
                              hipStream_t stream) {
    (void)n_in; (void)out_size; (void)ws_size;
    const float* f0      = (const float*)d_in[0];
    const float* f1      = (const float*)d_in[1];
    const float* f2      = (const float*)d_in[2];
    const float* anchors = (const float*)d_in[3];
    const float* imshape = (const float*)d_in[4];
    const int B = in_sizes[0] / (255 * 19 * 19);

    char* ws = (char*)d_ws;
    size_t o = 0;
    unsigned short* keybuf = (unsigned short*)(ws + o);
    o += (size_t)B * NCLS * KPAD * sizeof(unsigned short);   // 58.2 MB
    float4* boxes  = (float4*)(ws + o); o += (size_t)B * NTOT * sizeof(float4);
    float*  conf_q = (float*)(ws + o);  o += (size_t)B * KPAD * sizeof(float);
    float*  top_s  = (float*)(ws + o);  o += (size_t)B * NCLS * TOPK * sizeof(float);
    float4* top_b  = (float4*)(ws + o); o += (size_t)B * NCLS * TOPK * sizeof(float4);
    float*  cand   = (float*)(ws + o);  o += (size_t)B * NCLS * TOPK * sizeof(float);
    float*  out    = (float*)d_out;

    const int total = B * NTOT;
    k_decode<<<(total + 255) / 256, 256, 0, stream>>>(f0, f1, f2, anchors, imshape,
                                                      boxes, conf_q, total);
    const int stotal = B * SEG_T;
    k_score<<<(stotal + 255) / 256, 256, 0, stream>>>(f0, f1, f2, conf_q,
                                                      keybuf, stotal);
    k_topk<<<B * NCLS, 512, 0, stream>>>(f0, f1, f2, conf_q, keybuf, boxes,
                                         top_s, top_b);
    k_nms<<<(B * NCLS) / 4, 256, 0, stream>>>(top_s, top_b, cand);
    k_final<<<B, 256, 0, stream>>>(cand, top_b, out);
}

// Round 6
// 265.693 us; speedup vs baseline: 1.3827x; 1.1159x over previous
//
#include <hip/hip_runtime.h>
#include <hip/hip_bf16.h>

// ---------------------------------------------------------------------------
// YOLOv3 post-processing pipeline (round 6):
//   K1 decode : plane-major coalesced feature reads; conf written in q-order
//   K2 score  : streaming 1-thread-=-4-keys float4/ushort4 kernel
//   K3 topk   : keys loaded ONCE into 24 VGPRs (hist + collect from regs),
//               rank-by-count instead of bitonic sort (2 barriers vs 45),
//               FUSED greedy NMS on wave 0 -> writes cand directly
//   K4 final  : per-image top-100 of 8000, rank-by-count epilogue
// ---------------------------------------------------------------------------

#define NTOT   22743      // 3*(19^2 + 38^2 + 76^2)
#define NCLS   80
#define TOPK   100
#define KPAD   22752      // row stride for keybuf/conf (16B aligned, 8-div)
#define NVEC   2842       // full uint4 groups per key row (22736 keys)
#define Q_L1   17328
#define Q_L0   21660
#define SCORE_THR 0.2f
#define NMS_THR   0.3f

__device__ __forceinline__ float sig_exact(float x) {
    return 1.0f / (1.0f + expf(-x));          // precise OCML expf + IEEE div
}
__device__ __forceinline__ float sig_fast(float x) {
    // monotone surrogate, rel err ~1e-6 << 2^-7 bin margin
    return __builtin_amdgcn_rcpf(1.0f + __expf(-x));
}

// -------------------------- K1: decode (plane-major) ----------------------
__global__ __launch_bounds__(256) void k_decode(
    const float* __restrict__ f0, const float* __restrict__ f1,
    const float* __restrict__ f2, const float* __restrict__ anchors,
    const float* __restrict__ imshape, float4* __restrict__ boxes,
    float* __restrict__ conf_q, int total) {
    int gid = blockIdx.x * 256 + threadIdx.x;
    if (gid >= total) return;
    int b = gid / NTOT; int p = gid - b * NTOT;

    const float* f; int ghw, gw, l, off, a, s;
    if (p < 1083)      { f=f0; off=0;    ghw=361;  gw=19; l=0; int r=p;      a=r/361;  s=r-a*361;  }
    else if (p < 5415) { f=f1; off=1083; ghw=1444; gw=38; l=1; int r=p-1083; a=r/1444; s=r-a*1444; }
    else               { f=f2; off=5415; ghw=5776; gw=76; l=2; int r=p-5415; a=r/5776; s=r-a*5776; }
    int y = s / gw, x = s - y * gw;

    const float* q = f + ((size_t)(b * 255 + a * 85) * ghw + s);
    float tx = q[0], ty = q[ghw], tw = q[2*ghw], th = q[3*ghw], tc = q[4*ghw];

    int arow = (2 - l) * 3 + a;
    float aw = anchors[arow * 2], ah = anchors[arow * 2 + 1];
    float imh = imshape[0], imw = imshape[1];
    float gf = (float)gw;                       // gh == gw for all layers

    float bxx = (sig_exact(tx) + (float)x) / gf;
    float bxy = (sig_exact(ty) + (float)y) / gf;
    float bw  = expf(tw) * aw / 608.0f;
    float bh  = expf(th) * ah / 608.0f;

    float r  = fminf(608.0f / imh, 608.0f / imw);
    float nh = rintf(imh * r), nw = rintf(imw * r);
    float offy = (608.0f - nh) / 2.0f / 608.0f;
    float offx = (608.0f - nw) / 2.0f / 608.0f;
    float scy = 608.0f / nh, scx = 608.0f / nw;

    float cy = (bxy - offy) * scy;
    float cx = (bxx - offx) * scx;
    float hh = bh * scy, ww = bw * scx;

    int n = off + 3 * s + a;                    // anchor-major output index
    boxes[(size_t)b * NTOT + n] =
        make_float4((cy - hh / 2.0f) * imh, (cx - ww / 2.0f) * imw,
                    (cy + hh / 2.0f) * imh, (cx + ww / 2.0f) * imw);
    int qi = (l == 2) ? (a * 5776 + s)
           : (l == 1) ? (Q_L1 + a * 1444 + s)
                      : (Q_L0 + a * 361 + s);
    conf_q[(size_t)b * KPAD + qi] = sig_exact(tc);
}

// -------------------------- K2: score (streaming) -------------------------
#define SEG_A  346560
#define SEG_AB 433200
#define SEG_T  519840
__global__ __launch_bounds__(256) void k_score(
    const float* __restrict__ f0, const float* __restrict__ f1,
    const float* __restrict__ f2, const float* __restrict__ conf_q,
    unsigned short* __restrict__ keybuf, int total) {
    int gid = blockIdx.x * 256 + threadIdx.x;
    if (gid >= total) return;
    const int b = gid / SEG_T;
    const int w = gid - b * SEG_T;

    if (w < SEG_AB) {                       // vectorized: layer 2 or layer 1
        const float* f; int a, c, s, qbase, ghw;
        if (w < SEG_A) {                    // layer 2: 80*1444 float4 per a
            a = w / 115520; int r = w - a * 115520;
            c = r / 1444;   s = (r - c * 1444) * 4;
            f = f2; ghw = 5776; qbase = a * 5776;
        } else {                            // layer 1: 80*361 float4 per a
            int t = w - SEG_A;
            a = t / 28880;  int r = t - a * 28880;
            c = r / 361;    s = (r - c * 361) * 4;
            f = f1; ghw = 1444; qbase = Q_L1 + a * 1444;
        }
        const float4 lg = *(const float4*)(f + ((size_t)(b * 255 + a * 85 + 5 + c) * ghw + s));
        const float4 cf = *(const float4*)(conf_q + (size_t)b * KPAD + qbase + s);
        ushort4 k;
        k.x = (unsigned short)(__float_as_uint(cf.x * sig_fast(lg.x)) >> 16);
        k.y = (unsigned short)(__float_as_uint(cf.y * sig_fast(lg.y)) >> 16);
        k.z = (unsigned short)(__float_as_uint(cf.z * sig_fast(lg.z)) >> 16);
        k.w = (unsigned short)(__float_as_uint(cf.w * sig_fast(lg.w)) >> 16);
        *(ushort4*)(keybuf + ((size_t)(b * NCLS + c)) * KPAD + qbase + s) = k;
    } else {                                // layer 0: scalar
        int t = w - SEG_AB;
        int a = t / 28880;  int r = t - a * 28880;
        int c = r / 361;    int s = r - c * 361;
        int qi = Q_L0 + a * 361 + s;
        float lg = f0[((size_t)(b * 255 + a * 85 + 5 + c) * 361 + s)];
        float cf = conf_q[(size_t)b * KPAD + qi];
        keybuf[((size_t)(b * NCLS + c)) * KPAD + qi] =
            (unsigned short)(__float_as_uint(cf * sig_fast(lg)) >> 16);
    }
}

// ------------------ shared select helpers ---------------------------------
__device__ void find_pivot(unsigned* hist, int H, unsigned target,
                           unsigned* suf, unsigned* sh_p, unsigned* sh_above) {
    const int tid = threadIdx.x;
    const int per = H >> 8;
    if (tid < 256) {
        unsigned acc = 0;
        for (int u = 0; u < per; ++u) acc += hist[tid * per + u];
        suf[tid] = acc;
    }
    __syncthreads();
    for (int off = 1; off < 256; off <<= 1) {
        unsigned v = 0;
        if (tid < 256) v = (tid + off < 256) ? suf[tid + off] : 0u;
        __syncthreads();
        if (tid < 256) suf[tid] += v;
        __syncthreads();
    }
    if (tid < 256) {
        unsigned mysuf = suf[tid];
        unsigned nxt = (tid == 255) ? 0u : suf[tid + 1];
        if (mysuf >= target && nxt < target) {
            unsigned above = nxt;
            for (int h = tid * per + per - 1; h >= tid * per; --h) {
                unsigned c2 = above + hist[h];
                if (c2 >= target) { *sh_p = (unsigned)h; *sh_above = above; break; }
                above = c2;
            }
        }
    }
    __syncthreads();
}

// -------------------------- K3: per-class top-100 + fused NMS -------------
__device__ __forceinline__ void collect_cand(
    int b, int c, int q, const float* __restrict__ f0,
    const float* __restrict__ f1, const float* __restrict__ f2,
    const float* __restrict__ conf_q, unsigned long long* buf,
    unsigned* sh_cnt) {
    int a, s, nbase, ghw;
    const float* f;
    if (q < Q_L1)      { a = q / 5776;  s = q - a * 5776;  f = f2; ghw = 5776; nbase = 5415; }
    else if (q < Q_L0) { int r = q - Q_L1; a = r / 1444; s = r - a * 1444; f = f1; ghw = 1444; nbase = 1083; }
    else               { int r = q - Q_L0; a = r / 361;  s = r - a * 361;  f = f0; ghw = 361;  nbase = 0;    }
    float t  = f[((size_t)(b * 255 + a * 85 + 5 + c)) * ghw + s];
    float cf = conf_q[(size_t)b * KPAD + q];
    float sce = cf * sig_exact(t);
    int n = nbase + 3 * s + a;
    unsigned slot = atomicAdd(sh_cnt, 1u);
    if (slot < 512)
        buf[slot] = (((unsigned long long)__float_as_uint(sce)) << 32)
                    | (unsigned)(~n);
}

__global__ __launch_bounds__(512, 8) void k_topk(
    const float* __restrict__ f0, const float* __restrict__ f1,
    const float* __restrict__ f2, const float* __restrict__ conf_q,
    const unsigned short* __restrict__ keybuf,
    const float4* __restrict__ boxes, float4* __restrict__ top_b,
    float* __restrict__ cand) {
    __shared__ unsigned int histp[4096];           // packed u16x2: 8192 bins, 16 KB
    __shared__ unsigned long long buf[512];        // 4 KB
    __shared__ unsigned int wsum[4];
    __shared__ float sb_y1[TOPK], sb_x1[TOPK], sb_y2[TOPK], sb_x2[TOPK], sb_s[TOPK];
    __shared__ unsigned int sh_p, sh_cnt;

    const int tid = threadIdx.x;
    const int row = blockIdx.x;
    const int b = row / NCLS, c = row - b * NCLS;
    const unsigned short* kr = keybuf + (size_t)row * KPAD;
    const uint4* kv = (const uint4*)kr;            // 8 keys per load

    for (int i = tid; i < 4096; i += 512) histp[i] = 0;
    if (tid == 0) sh_cnt = 0;
    __syncthreads();

    // load ALL keys once: 6 uint4 (48 keys) per thread stay in VGPRs
    uint4 v[6];
    bool  val[6];
    #pragma unroll
    for (int k = 0; k < 6; ++k) {
        int g = tid + k * 512;
        val[k] = (g < NVEC);
        v[k] = val[k] ? kv[g] : make_uint4(0, 0, 0, 0);
    }
    const bool hastail = (tid < NTOT - NVEC * 8);  // 7-key tail
    unsigned tailk = hastail ? (unsigned)kr[NVEC * 8 + tid] : 0u;

    // pass 1: packed histogram of key>>1 (8192 bins) from registers
    #pragma unroll
    for (int k = 0; k < 6; ++k) if (val[k]) {
        unsigned ks[8] = { v[k].x & 0xFFFFu, v[k].x >> 16, v[k].y & 0xFFFFu, v[k].y >> 16,
                           v[k].z & 0xFFFFu, v[k].z >> 16, v[k].w & 0xFFFFu, v[k].w >> 16 };
        #pragma unroll
        for (int j = 0; j < 8; ++j)
            atomicAdd(&histp[ks[j] >> 2], 1u << (((ks[j] >> 1) & 1u) * 16));
    }
    if (hastail) atomicAdd(&histp[tailk >> 2], 1u << (((tailk >> 1) & 1u) * 16));
    __syncthreads();

    // pivot: group t (tid<256) covers bins [t*32,t*32+32) = words [t*16,t*16+16)
    {
        const int lane = tid & 63;
        unsigned own = 0;
        if (tid < 256) {
            #pragma unroll
            for (int u = 0; u < 16; ++u) {
                unsigned w = histp[tid * 16 + u];
                own += (w & 0xFFFFu) + (w >> 16);
            }
        }
        unsigned acc = own;                        // wave-level suffix scan
        #pragma unroll
        for (int d = 1; d < 64; d <<= 1) {
            unsigned vv = __shfl_down(acc, d, 64);
            if (lane + d < 64) acc += vv;
        }
        if (tid < 256 && lane == 0) wsum[tid >> 6] = acc;
        __syncthreads();
        if (tid < 256) {
            unsigned tail = 0;
            for (int w2 = (tid >> 6) + 1; w2 < 4; ++w2) tail += wsum[w2];
            unsigned suft = acc + tail;            // suffix incl own group
            unsigned nxt  = suft - own;            // suffix of groups above
            if (suft >= TOPK && nxt < TOPK) {
                unsigned above = nxt;
                for (int bb = 31; bb >= 0; --bb) {
                    unsigned w = histp[tid * 16 + (bb >> 1)];
                    unsigned cnt = (bb & 1) ? (w >> 16) : (w & 0xFFFFu);
                    if (above + cnt >= TOPK) { sh_p = (unsigned)(tid * 32 + bb); break; }
                    above += cnt;
                }
            }
        }
        __syncthreads();
    }
    const unsigned kthr = sh_p > 0 ? ((sh_p - 1) << 1) : 0u;  // one-bin margin

    // pass 2: collect candidates FROM REGISTERS, exact rescore
    #pragma unroll
    for (int k = 0; k < 6; ++k) if (val[k]) {
        unsigned ks[8] = { v[k].x & 0xFFFFu, v[k].x >> 16, v[k].y & 0xFFFFu, v[k].y >> 16,
                           v[k].z & 0xFFFFu, v[k].z >> 16, v[k].w & 0xFFFFu, v[k].w >> 16 };
        #pragma unroll
        for (int j = 0; j < 8; ++j)
            if (ks[j] >= kthr)
                collect_cand(b, c, (tid + k * 512) * 8 + j, f0, f1, f2, conf_q, buf, &sh_cnt);
    }
    if (hastail && tailk >= kthr)
        collect_cand(b, c, NVEC * 8 + tid, f0, f1, f2, conf_q, buf, &sh_cnt);
    __syncthreads();

    // rank-by-count (keys unique: (score_bits, ~n)); M >= 100 by construction
    const int M = (int)min(sh_cnt, 512u);
    if (tid < M) {
        unsigned long long mykey = buf[tid];
        int rank = 0;
        for (int j = 0; j < M; ++j) rank += (buf[j] > mykey);   // LDS broadcast
        if (rank < TOPK) {
            int n = (int)(~(unsigned)mykey);
            float4 bx = boxes[(size_t)b * NTOT + n];
            sb_y1[rank] = bx.x; sb_x1[rank] = bx.y;
            sb_y2[rank] = bx.z; sb_x2[rank] = bx.w;
            sb_s[rank]  = __uint_as_float((unsigned)(mykey >> 32));
            top_b[(size_t)row * TOPK + rank] = bx;
        }
    }
    __syncthreads();

    // fused greedy NMS on wave 0 (reference-exact op order)
    if (tid < 64) {
        const int j0 = tid, j1 = tid + 64;
        const bool v1 = (j1 < TOPK);
        float y10 = sb_y1[j0], x10 = sb_x1[j0], y20 = sb_y2[j0], x20 = sb_x2[j0];
        float s0 = sb_s[j0];
        float y11 = v1 ? sb_y1[j1] : 0.f, x11 = v1 ? sb_x1[j1] : 0.f;
        float y21 = v1 ? sb_y2[j1] : 0.f, x21 = v1 ? sb_x2[j1] : 0.f;
        float s1 = v1 ? sb_s[j1] : -1.0f;
        float ar0 = fmaxf(y20 - y10, 0.f) * fmaxf(x20 - x10, 0.f);
        float ar1 = fmaxf(y21 - y11, 0.f) * fmaxf(x21 - x11, 0.f);
        int sup0 = 0, sup1 = 0;
        for (int i = 0; i < TOPK; ++i) {
            float yi1 = sb_y1[i], xi1 = sb_x1[i], yi2 = sb_y2[i], xi2 = sb_x2[i];
            float si = sb_s[i];
            int supi = (i < 64) ? __shfl(sup0, i, 64) : __shfl(sup1, i - 64, 64);
            bool keep_i = (si >= SCORE_THR) && (supi == 0);
            if (keep_i) {
                float ari = fmaxf(yi2 - yi1, 0.f) * fmaxf(xi2 - xi1, 0.f);
                if (j0 > i) {
                    float ty1 = fmaxf(yi1, y10), tx1 = fmaxf(xi1, x10);
                    float ty2 = fminf(yi2, y20), tx2 = fminf(xi2, x20);
                    float inter = fmaxf(ty2 - ty1, 0.f) * fmaxf(tx2 - tx1, 0.f);
                    float iou = inter / (ari + ar0 - inter + 1e-9f);
                    if (iou > NMS_THR) sup0 = 1;
                }
                if (v1 && j1 > i) {
                    float ty1 = fmaxf(yi1, y11), tx1 = fmaxf(xi1, x11);
                    float ty2 = fminf(yi2, y21), tx2 = fminf(xi2, x21);
                    float inter = fmaxf(ty2 - ty1, 0.f) * fmaxf(tx2 - tx1, 0.f);
                    float iou = inter / (ari + ar1 - inter + 1e-9f);
                    if (iou > NMS_THR) sup1 = 1;
                }
            }
        }
        cand[(size_t)row * TOPK + j0] = (s0 >= SCORE_THR && sup0 == 0) ? s0 : -1.0f;
        if (v1)
            cand[(size_t)row * TOPK + j1] = (s1 >= SCORE_THR && sup1 == 0) ? s1 : -1.0f;
    }
}

// -------------------------- K4: per-image top-100 -------------------------
__global__ __launch_bounds__(256) void k_final(
    const float* __restrict__ cand, const float4* __restrict__ top_b,
    float* __restrict__ out) {
    __shared__ float cs[8000];                     // 32 KB
    __shared__ unsigned int hist[4096];            // 16 KB
    __shared__ unsigned long long buf[512];
    __shared__ unsigned int suf[256];
    __shared__ unsigned int sh_kp, sh_p1, sh_above1, sh_p2, sh_above2, sh_cnt;

    const int tid = threadIdx.x, b = blockIdx.x;
    if (tid == 0) { sh_kp = 0; sh_cnt = 0; }
    for (int i = tid; i < 4096; i += 256) hist[i] = 0;
    __syncthreads();

    unsigned lk = 0;
    for (int i = tid; i < 8000; i += 256) {
        float v = cand[b * 8000 + i];
        cs[i] = v;
        if (v > -0.5f) lk++;
    }
    atomicAdd(&sh_kp, lk);
    __syncthreads();
    unsigned Kp = sh_kp;

    if (Kp >= TOPK) {
        for (int i = tid; i < 8000; i += 256)
            if (cs[i] > -0.5f) atomicAdd(&hist[__float_as_uint(cs[i]) >> 19], 1u);
        __syncthreads();
        find_pivot(hist, 2048, TOPK, suf, &sh_p1, &sh_above1);
        unsigned p1 = sh_p1, above1 = sh_above1;
        for (int i = tid; i < 4096; i += 256) hist[i] = 0;
        __syncthreads();
        for (int i = tid; i < 8000; i += 256) {
            float v = cs[i];
            if (v > -0.5f) {
                unsigned bits = __float_as_uint(v);
                if ((bits >> 19) == p1) atomicAdd(&hist[(bits >> 7) & 0xFFFu], 1u);
            }
        }
        __syncthreads();
        find_pivot(hist, 4096, TOPK - above1, suf, &sh_p2, &sh_above2);
        unsigned p2 = sh_p2;
        for (int i = tid; i < 8000; i += 256) {
            float v = cs[i];
            if (v > -0.5f) {
                unsigned bits = __float_as_uint(v);
                unsigned b1 = bits >> 19;
                if (b1 > p1 || (b1 == p1 && ((bits >> 7) & 0xFFFu) >= p2)) {
                    unsigned slot = atomicAdd(&sh_cnt, 1u);
                    if (slot < 512)
                        buf[slot] = (((unsigned long long)bits) << 32) | (unsigned)(~i);
                }
            }
        }
    } else {
        // < 100 kept: all kept + smallest flat indices among exact -1.0 ties
        for (int i = tid; i < 8000; i += 256) {
            float v = cs[i];
            if (v > -0.5f) {
                unsigned slot = atomicAdd(&sh_cnt, 1u);
                buf[slot] = (((unsigned long long)__float_as_uint(v)) << 32) | (unsigned)(~i);
            }
        }
        __syncthreads();
        if (tid == 0) {
            unsigned need = TOPK - Kp, got = 0;
            for (int i = 0; i < 8000 && got < need; ++i)
                if (cs[i] <= -0.5f) { buf[Kp + got] = (unsigned)(~i); got++; }
        }
    }
    __syncthreads();

    // rank-by-count epilogue (keys unique via distinct ~i)
    const int M2 = (Kp >= TOPK) ? (int)min(sh_cnt, 512u) : (int)TOPK;
    for (int i = tid; i < M2; i += 256) {
        unsigned long long key = buf[i];
        int rank = 0;
        for (int j = 0; j < M2; ++j) rank += (buf[j] > key);
        if (rank < TOPK) {
            int fi = (int)(~(unsigned)key);
            int c = fi / TOPK; int kk = fi - c * TOPK;
            float4 bb = top_b[((size_t)b * NCLS + c) * TOPK + kk];
            int base = (b * TOPK + rank) * 6;
            out[base + 0] = bb.x; out[base + 1] = bb.y;
            out[base + 2] = bb.z; out[base + 3] = bb.w;
            out[base + 4] = cs[fi]; out[base + 5] = (float)c;
        }
    }
}

// ---------------------------------------------------------------------------
extern "C" void kernel_launch(void* const* d_in, const int* in_sizes, int n_in,
                              void* d_out, int out_size, void* d_ws, size_t ws_size,
                              hipStream_t stream) {
    (void)n_in; (void)out_size; (void)ws_size;
    const float* f0      = (const float*)d_in[0];
    const float* f1      = (const float*)d_in[1];
    const float* f2      = (const float*)d_in[2];
    const float* anchors = (const float*)d_in[3];
    const float* imshape = (const float*)d_in[4];
    const int B = in_sizes[0] / (255 * 19 * 19);

    char* ws = (char*)d_ws;
    size_t o = 0;
    unsigned short* keybuf = (unsigned short*)(ws + o);
    o += (size_t)B * NCLS * KPAD * sizeof(unsigned short);   // 58.2 MB
    float4* boxes  = (float4*)(ws + o); o += (size_t)B * NTOT * sizeof(float4);
    float*  conf_q = (float*)(ws + o);  o += (size_t)B * KPAD * sizeof(float);
    float4* top_b  = (float4*)(ws + o); o += (size_t)B * NCLS * TOPK * sizeof(float4);
    float*  cand   = (float*)(ws + o);  o += (size_t)B * NCLS * TOPK * sizeof(float);
    float*  out    = (float*)d_out;

    const int total = B * NTOT;
    k_decode<<<(total + 255) / 256, 256, 0, stream>>>(f0, f1, f2, anchors, imshape,
                                                      boxes, conf_q, total);
    const int stotal = B * SEG_T;
    k_score<<<(stotal + 255) / 256, 256, 0, stream>>>(f0, f1, f2, conf_q,
                                                      keybuf, stotal);
    k_topk<<<B * NCLS, 512, 0, stream>>>(f0, f1, f2, conf_q, keybuf, boxes,
                                         top_b, cand);
    k_final<<<B, 256, 0, stream>>>(cand, top_b, out);
}